// Round 6
// baseline (126.447 us; speedup 1.0000x reference)
//
#include <hip/hip_runtime.h>
#include <hip/hip_bf16.h>

// N=2048, D_IN=128, H=256, D_EMB=64
// inputs: 0:x 1:adj(unused) 2:W0 3:b0 4:W1 5:b1 6:W2 7:b2 8:temp 9:theta
// d_out: out[2048*128] then adj_wts[2048*2048]
//
// R18: 2-launch endpoint of the overhead-reduction direction (R16 proved more
// blocks/partials = worse; R17 proved fewer = better). k2full: 256 blocks x
// 512 thr, block = 8-row i-tile x FULL 2048 j (16 strips, double-buffered P,
// 1 barrier/strip). deg completes in-block -> out written directly; k3,
// outPart, degPart all eliminated. MFMA rows 8-15 computed-and-discarded
// (MFMA is ~0.5% of budget). k1 unchanged (proven R14/R15/R17 form).

typedef short bf16x8 __attribute__((ext_vector_type(8)));
typedef float f32x4 __attribute__((ext_vector_type(4)));

__device__ __forceinline__ unsigned short f2bf(float f) {
    unsigned u = __float_as_uint(f);
    unsigned r = u + 0x7fffu + ((u >> 16) & 1u);
    return (unsigned short)(r >> 16);
}

// pack 8 f32 -> bf16x8 with round-half-up
__device__ __forceinline__ bf16x8 pack_rne8(const float* p) {
    union { unsigned u[4]; bf16x8 v; } r;
    #pragma unroll
    for (int i = 0; i < 4; ++i) {
        unsigned lo = __float_as_uint(p[2 * i]) + 0x8000u;
        unsigned hi = __float_as_uint(p[2 * i + 1]) + 0x8000u;
        r.u[i] = __builtin_amdgcn_perm(hi, lo, 0x07060302u);
    }
    return r.v;
}

// truncation-pack (for the P tile in k2)
__device__ __forceinline__ bf16x8 pack_bf8(const float* p) {
    union { unsigned u[4]; bf16x8 v; } r;
    #pragma unroll
    for (int i = 0; i < 4; ++i)
        r.u[i] = __builtin_amdgcn_perm(__float_as_uint(p[2 * i + 1]),
                                       __float_as_uint(p[2 * i]), 0x07060302u);
    return r.v;
}

// ---------------- Kernel 1: fused MLP via MFMA, 256 blocks x 4 waves ----------------
// block = (i-tile = bid>>1, role = bid&1).
// role 0: GEMM0 (x@W0, 16x256) -> LDS -> GEMM1 (emb) + sq.
// role 1: GEMM2 (x@W2) only — no LDS, no barrier. (Proven R14/R15/R17 path.)
__global__ __launch_bounds__(256, 2) void k1_mfma(
    const float* __restrict__ x,
    const float* __restrict__ W0, const float* __restrict__ b0,
    const float* __restrict__ W1, const float* __restrict__ b1,
    const float* __restrict__ W2, const float* __restrict__ b2,
    unsigned short* __restrict__ emb_bf,   // [2048][64] bf16
    unsigned short* __restrict__ xlT_bf,   // [128][2048] bf16
    float* __restrict__ sq)                // [2048]
{
    constexpr int LDO = 264;               // out_x LDS stride (bf16 elems)
    __shared__ unsigned short oxb[16 * LDO];
    __shared__ float sqs[4][16];

    const int t = threadIdx.x;
    const int lane = t & 63;
    const int w = t >> 6;      // wave 0..3
    const int m = lane & 15;
    const int q = lane >> 4;
    const int tile = blockIdx.x >> 1;
    const int role = blockIdx.x & 1;
    const int i0 = tile * 16;

    // A-fragments of x (rows i0+m, K=128) — needed by both roles
    bf16x8 ax[4];
    #pragma unroll
    for (int kb = 0; kb < 4; ++kb) {
        float xf[8];
        *(f32x4*)&xf[0] = *(const f32x4*)(x + (size_t)(i0 + m) * 128 + kb * 32 + q * 8);
        *(f32x4*)&xf[4] = *(const f32x4*)(x + (size_t)(i0 + m) * 128 + kb * 32 + q * 8 + 4);
        ax[kb] = pack_rne8(xf);
    }

    if (role == 0) {
        // prefetch W1 fragments (independent of GEMM0)
        const int h1 = w * 16 + m;
        const float bias1 = b1[h1];
        bf16x8 wp[8];
        #pragma unroll
        for (int kb = 0; kb < 8; ++kb) {
            float wf[8];
            #pragma unroll
            for (int j = 0; j < 8; ++j) wf[j] = W1[(size_t)(kb * 32 + q * 8 + j) * 64 + h1];
            wp[kb] = pack_rne8(wf);
        }

        // GEMM0: out_x = relu(x @ W0 + b0); wave w covers cols w*64..w*64+63
        #pragma unroll
        for (int hh = 0; hh < 4; ++hh) {
            const int h = (w * 4 + hh) * 16 + m;
            float bb = b0[h];
            f32x4 acc = {bb, bb, bb, bb};
            #pragma unroll
            for (int kb = 0; kb < 4; ++kb) {
                float wf[8];
                #pragma unroll
                for (int j = 0; j < 8; ++j) wf[j] = W0[(size_t)(kb * 32 + q * 8 + j) * 256 + h];
                acc = __builtin_amdgcn_mfma_f32_16x16x32_bf16(ax[kb], pack_rne8(wf), acc, 0, 0, 0);
            }
            #pragma unroll
            for (int r = 0; r < 4; ++r)
                oxb[(q * 4 + r) * LDO + h] = f2bf(fmaxf(acc[r], 0.0f));
        }
        __syncthreads();

        // GEMM1: emb = relu(out_x @ W1 + b1), wave w -> cols w*16..w*16+15
        f32x4 acc = {bias1, bias1, bias1, bias1};
        #pragma unroll
        for (int kb = 0; kb < 8; ++kb) {
            bf16x8 af = *(const bf16x8*)(&oxb[m * LDO + kb * 32 + q * 8]);
            acc = __builtin_amdgcn_mfma_f32_16x16x32_bf16(af, wp[kb], acc, 0, 0, 0);
        }
        float s2[4];
        #pragma unroll
        for (int r = 0; r < 4; ++r) {
            float e = fmaxf(acc[r], 0.0f);
            emb_bf[(size_t)(i0 + q * 4 + r) * 64 + h1] = f2bf(e);
            s2[r] = e * e;
        }
        #pragma unroll
        for (int r = 0; r < 4; ++r) {
            float v = s2[r];
            v += __shfl_xor(v, 1);
            v += __shfl_xor(v, 2);
            v += __shfl_xor(v, 4);
            v += __shfl_xor(v, 8);
            if (m == 0) sqs[w][q * 4 + r] = v;
        }
        __syncthreads();
        if (t < 16)
            sq[i0 + t] = sqs[0][t] + sqs[1][t] + sqs[2][t] + sqs[3][t];
    } else {
        // GEMM2: x_last = x @ W2 + b2, wave w -> cols w*32..w*32+31
        bf16x8 wp[8];
        #pragma unroll
        for (int hh = 0; hh < 2; ++hh) {
            const int c = (w * 2 + hh) * 16 + m;
            #pragma unroll
            for (int kb = 0; kb < 4; ++kb) {
                float wf[8];
                #pragma unroll
                for (int j = 0; j < 8; ++j) wf[j] = W2[(size_t)(kb * 32 + q * 8 + j) * 128 + c];
                wp[hh * 4 + kb] = pack_rne8(wf);
            }
        }
        #pragma unroll
        for (int hh = 0; hh < 2; ++hh) {
            const int c = (w * 2 + hh) * 16 + m;
            float bb = b2[c];
            f32x4 acc = {bb, bb, bb, bb};
            #pragma unroll
            for (int kb = 0; kb < 4; ++kb)
                acc = __builtin_amdgcn_mfma_f32_16x16x32_bf16(ax[kb], wp[hh * 4 + kb], acc, 0, 0, 0);
            uint2 pk;
            pk.x = (unsigned)f2bf(acc[0]) | ((unsigned)f2bf(acc[1]) << 16);
            pk.y = (unsigned)f2bf(acc[2]) | ((unsigned)f2bf(acc[3]) << 16);
            *(uint2*)(&xlT_bf[(size_t)c * 2048 + i0 + q * 4]) = pk;
        }
    }
}

// ---------------- Kernel 2: fused adjacency + A@x_last + normalize, full rows ----------------
// 256 blocks x 512 thr (8 waves). Block = 8-row i-tile x FULL 2048 cols,
// 16 strips of 128, double-buffered P, ONE barrier per strip. deg completes
// in-block -> out written directly. No partials, no fences, no atomics.
// MFMA C-rows 8-15 are duplicates/garbage and discarded (q<2 predicates).
__global__ __launch_bounds__(512, 2) void k2full(
    const unsigned short* __restrict__ emb_bf,
    const unsigned short* __restrict__ xlT_bf,
    const float* __restrict__ sq,
    const float* __restrict__ tempp, const float* __restrict__ thetap,
    float* __restrict__ adjw,      // [2048][2048] f32
    float* __restrict__ out)       // [2048][128] f32 final
{
    constexpr int LDP = 132;
    __shared__ float Pt[2][8 * LDP];
    __shared__ float degS[8][8];
    __shared__ float degF[8];

    const int t = threadIdx.x;
    const int lane = t & 63;
    const int w = t >> 6;          // wave 0..7
    const int m = lane & 15;
    const int q = lane >> 4;       // 0..3; only q<2 rows are real (8-row tile)
    const int i0 = blockIdx.x * 8;
    const float scale = 1.0f + tempp[0];
    const float bias = 5.0f + thetap[0];

    // A-fragments: emb rows i0 + (m&7); m>=8 duplicates rows 0..7 (C-rows
    // 8..15 then duplicate C-rows 0..7 and are discarded) — avoids OOB on
    // the last tile.
    const int arow = i0 + (m & 7);
    bf16x8 a0 = *(const bf16x8*)(emb_bf + (size_t)arow * 64 + q * 8);
    bf16x8 a1 = *(const bf16x8*)(emb_bf + (size_t)arow * 64 + 32 + q * 8);
    float sqIr[4];
    #pragma unroll
    for (int r = 0; r < 4; ++r) sqIr[r] = sq[i0 + ((q * 4 + r) & 7)];

    f32x4 accO = {0.f, 0.f, 0.f, 0.f};   // out rows q*4+r (q<2), col w*16+m
    float dega[4] = {0.f, 0.f, 0.f, 0.f};
    const int cg = w * 16;                // output col-group (AX)

    for (int jt = 0; jt < 16; ++jt) {
        const int j0 = jt * 128;
        float* P = &Pt[jt & 1][0];

        // prefetch AX B-fragments (xlT rows cg..cg+15, k = strip cols)
        bf16x8 xb[4];
        #pragma unroll
        for (int s = 0; s < 4; ++s)
            xb[s] = *(const bf16x8*)(xlT_bf + (size_t)(cg + m) * 2048 + j0 + s * 32 + q * 8);

        // S phase: wave w computes strip cols w*16..w*16+15
        {
            const int col = w * 16 + m;
            const int gcol = j0 + col;
            const unsigned short* ebj = emb_bf + (size_t)gcol * 64;
            bf16x8 b0 = *(const bf16x8*)(ebj + q * 8);
            bf16x8 b1 = *(const bf16x8*)(ebj + 32 + q * 8);
            f32x4 S = {0.f, 0.f, 0.f, 0.f};
            S = __builtin_amdgcn_mfma_f32_16x16x32_bf16(a0, b0, S, 0, 0, 0);
            S = __builtin_amdgcn_mfma_f32_16x16x32_bf16(a1, b1, S, 0, 0, 0);

            const float csqJ = sq[gcol];
            if (q < 2) {
                #pragma unroll
                for (int r = 0; r < 4; ++r) {
                    int grow = i0 + q * 4 + r;
                    float dist = 2.0f * S[r] - sqIr[r] - csqJ;
                    float z = scale * dist + bias;
                    float p = __builtin_amdgcn_rcpf(1.0f + __expf(-z));
                    if (grow == gcol) p += 1.0f;
                    dega[r] += p;
                    P[(q * 4 + r) * LDP + col] = p;
                }
            }
        }
        __syncthreads();

        // adjw store: 8 rows x 128 cols. 64 lanes x float2 = 512B contiguous
        // per row -> full 128B lines.
        {
            int row = t >> 6;            // 0..7
            int c = t & 63;              // float2 col 0..63
            float2 v = *(const float2*)(&P[row * LDP + c * 2]);
            *(float2*)(adjw + (size_t)(i0 + row) * 2048 + j0 + c * 2) = v;
        }

        // AX: accO += P(8x128) @ xlT(128 x 16-col-group), K=128.
        // A-rows m>=8 duplicate rows 0..7 (C-rows 8..15 discarded).
        #pragma unroll
        for (int s = 0; s < 4; ++s) {
            float af[8];
            *(f32x4*)(&af[0]) = *(const f32x4*)(&P[(m & 7) * LDP + s * 32 + q * 8]);
            *(f32x4*)(&af[4]) = *(const f32x4*)(&P[(m & 7) * LDP + s * 32 + q * 8 + 4]);
            bf16x8 aa = pack_bf8(af);
            accO = __builtin_amdgcn_mfma_f32_16x16x32_bf16(aa, xb[s], accO, 0, 0, 0);
        }
        // reads(jt) precede barrier(jt+1) in program order; S(jt+2) writes
        // this buffer only after barrier(jt+1) -> 1 barrier/strip is safe.
    }

    // deg: reduce over m-lanes within each (w,q<2,r), combine 8 waves via LDS
    #pragma unroll
    for (int r = 0; r < 4; ++r) {
        float v = dega[r];
        v += __shfl_xor(v, 1);
        v += __shfl_xor(v, 2);
        v += __shfl_xor(v, 4);
        v += __shfl_xor(v, 8);
        if (m == 0 && q < 2) degS[w][q * 4 + r] = v;
    }
    __syncthreads();
    if (t < 8) {
        float d = 0.f;
        #pragma unroll
        for (int ww = 0; ww < 8; ++ww) d += degS[ww][t];
        degF[t] = d;
    }
    __syncthreads();

    // out = relu(accO / deg), written directly (no partials, no k3)
    if (q < 2) {
        #pragma unroll
        for (int r = 0; r < 4; ++r) {
            float dinv = 1.0f / degF[q * 4 + r];
            out[(size_t)(i0 + q * 4 + r) * 128 + cg + m] = fmaxf(accO[r] * dinv, 0.f);
        }
    }
}

extern "C" void kernel_launch(void* const* d_in, const int* in_sizes, int n_in,
                              void* d_out, int out_size, void* d_ws, size_t ws_size,
                              hipStream_t stream) {
    (void)in_sizes; (void)n_in; (void)out_size; (void)ws_size;
    const float* x     = (const float*)d_in[0];
    const float* W0    = (const float*)d_in[2];
    const float* b0    = (const float*)d_in[3];
    const float* W1    = (const float*)d_in[4];
    const float* b1    = (const float*)d_in[5];
    const float* W2    = (const float*)d_in[6];
    const float* b2    = (const float*)d_in[7];
    const float* temp  = (const float*)d_in[8];
    const float* theta = (const float*)d_in[9];

    char* ws = (char*)d_ws;
    unsigned short* emb_bf = (unsigned short*)(ws);            // ->262144
    unsigned short* xlT_bf = (unsigned short*)(ws + 262144);   // ->786432
    float* sq      = (float*)(ws + 786432);                    // ->794624
    // total 794624 B — far below the proven >=9.25 MB workspace

    float* out  = (float*)d_out;              // [2048*128]
    float* adjw = (float*)d_out + 262144;     // [2048*2048]

    k1_mfma<<<256, 256, 0, stream>>>(x, W0, b0, W1, b1, W2, b2,
                                     emb_bf, xlT_bf, sq);
    k2full<<<256, 512, 0, stream>>>(emb_bf, xlT_bf, sq, temp, theta,
                                    adjw, out);
}

// Round 7
// 107.975 us; speedup vs baseline: 1.1711x; 1.1711x over previous
//
#include <hip/hip_runtime.h>
#include <hip/hip_bf16.h>

// N=2048, D_IN=128, H=256, D_EMB=64
// inputs: 0:x 1:adj(unused) 2:W0 3:b0 4:W1 5:b1 6:W2 7:b2 8:temp 9:theta
// d_out: out[2048*128] then adj_wts[2048*2048]
//
// R19 = R17 verbatim (proven best, 108.07 us). R18's 2-launch variant
// regressed (+18us: 2x strip/barrier count at half useful work per phase,
// 2x wasted MFMA rows, full-emb B-streams per block). Structural search
// exhausted: R12/R15/R17 (3 distinct minimal structures) converge at
// 108-110us while harness poison fills (256MiB @ ~44us, 74-77% HBM peak)
// dominate the timed window. This is the revert-to-optimum.

typedef short bf16x8 __attribute__((ext_vector_type(8)));
typedef float f32x4 __attribute__((ext_vector_type(4)));

__device__ __forceinline__ unsigned short f2bf(float f) {
    unsigned u = __float_as_uint(f);
    unsigned r = u + 0x7fffu + ((u >> 16) & 1u);
    return (unsigned short)(r >> 16);
}

// pack 8 f32 -> bf16x8 with round-half-up
__device__ __forceinline__ bf16x8 pack_rne8(const float* p) {
    union { unsigned u[4]; bf16x8 v; } r;
    #pragma unroll
    for (int i = 0; i < 4; ++i) {
        unsigned lo = __float_as_uint(p[2 * i]) + 0x8000u;
        unsigned hi = __float_as_uint(p[2 * i + 1]) + 0x8000u;
        r.u[i] = __builtin_amdgcn_perm(hi, lo, 0x07060302u);
    }
    return r.v;
}

// truncation-pack (for the already-rounded P tile in k2)
__device__ __forceinline__ bf16x8 pack_bf8(const float* p) {
    union { unsigned u[4]; bf16x8 v; } r;
    #pragma unroll
    for (int i = 0; i < 4; ++i)
        r.u[i] = __builtin_amdgcn_perm(__float_as_uint(p[2 * i + 1]),
                                       __float_as_uint(p[2 * i]), 0x07060302u);
    return r.v;
}

// ---------------- Kernel 1: fused MLP via MFMA, 256 blocks x 4 waves ----------------
// block = (i-tile = bid>>1, role = bid&1).
// role 0: GEMM0 (x@W0, 16x256) -> LDS -> GEMM1 (emb) + sq.
// role 1: GEMM2 (x@W2) only — no LDS, no barrier. (Proven R14/R15/R17 path.)
__global__ __launch_bounds__(256, 2) void k1_mfma(
    const float* __restrict__ x,
    const float* __restrict__ W0, const float* __restrict__ b0,
    const float* __restrict__ W1, const float* __restrict__ b1,
    const float* __restrict__ W2, const float* __restrict__ b2,
    unsigned short* __restrict__ emb_bf,   // [2048][64] bf16
    unsigned short* __restrict__ xlT_bf,   // [128][2048] bf16
    float* __restrict__ sq)                // [2048]
{
    constexpr int LDO = 264;               // out_x LDS stride (bf16 elems)
    __shared__ unsigned short oxb[16 * LDO];
    __shared__ float sqs[4][16];

    const int t = threadIdx.x;
    const int lane = t & 63;
    const int w = t >> 6;      // wave 0..3
    const int m = lane & 15;
    const int q = lane >> 4;
    const int tile = blockIdx.x >> 1;
    const int role = blockIdx.x & 1;
    const int i0 = tile * 16;

    // A-fragments of x (rows i0+m, K=128) — needed by both roles
    bf16x8 ax[4];
    #pragma unroll
    for (int kb = 0; kb < 4; ++kb) {
        float xf[8];
        *(f32x4*)&xf[0] = *(const f32x4*)(x + (size_t)(i0 + m) * 128 + kb * 32 + q * 8);
        *(f32x4*)&xf[4] = *(const f32x4*)(x + (size_t)(i0 + m) * 128 + kb * 32 + q * 8 + 4);
        ax[kb] = pack_rne8(xf);
    }

    if (role == 0) {
        // prefetch W1 fragments (independent of GEMM0)
        const int h1 = w * 16 + m;
        const float bias1 = b1[h1];
        bf16x8 wp[8];
        #pragma unroll
        for (int kb = 0; kb < 8; ++kb) {
            float wf[8];
            #pragma unroll
            for (int j = 0; j < 8; ++j) wf[j] = W1[(size_t)(kb * 32 + q * 8 + j) * 64 + h1];
            wp[kb] = pack_rne8(wf);
        }

        // GEMM0: out_x = relu(x @ W0 + b0); wave w covers cols w*64..w*64+63
        #pragma unroll
        for (int hh = 0; hh < 4; ++hh) {
            const int h = (w * 4 + hh) * 16 + m;
            float bb = b0[h];
            f32x4 acc = {bb, bb, bb, bb};
            #pragma unroll
            for (int kb = 0; kb < 4; ++kb) {
                float wf[8];
                #pragma unroll
                for (int j = 0; j < 8; ++j) wf[j] = W0[(size_t)(kb * 32 + q * 8 + j) * 256 + h];
                acc = __builtin_amdgcn_mfma_f32_16x16x32_bf16(ax[kb], pack_rne8(wf), acc, 0, 0, 0);
            }
            #pragma unroll
            for (int r = 0; r < 4; ++r)
                oxb[(q * 4 + r) * LDO + h] = f2bf(fmaxf(acc[r], 0.0f));
        }
        __syncthreads();

        // GEMM1: emb = relu(out_x @ W1 + b1), wave w -> cols w*16..w*16+15
        f32x4 acc = {bias1, bias1, bias1, bias1};
        #pragma unroll
        for (int kb = 0; kb < 8; ++kb) {
            bf16x8 af = *(const bf16x8*)(&oxb[m * LDO + kb * 32 + q * 8]);
            acc = __builtin_amdgcn_mfma_f32_16x16x32_bf16(af, wp[kb], acc, 0, 0, 0);
        }
        float s2[4];
        #pragma unroll
        for (int r = 0; r < 4; ++r) {
            float e = fmaxf(acc[r], 0.0f);
            emb_bf[(size_t)(i0 + q * 4 + r) * 64 + h1] = f2bf(e);
            s2[r] = e * e;
        }
        #pragma unroll
        for (int r = 0; r < 4; ++r) {
            float v = s2[r];
            v += __shfl_xor(v, 1);
            v += __shfl_xor(v, 2);
            v += __shfl_xor(v, 4);
            v += __shfl_xor(v, 8);
            if (m == 0) sqs[w][q * 4 + r] = v;
        }
        __syncthreads();
        if (t < 16)
            sq[i0 + t] = sqs[0][t] + sqs[1][t] + sqs[2][t] + sqs[3][t];
    } else {
        // GEMM2: x_last = x @ W2 + b2, wave w -> cols w*32..w*32+31
        bf16x8 wp[8];
        #pragma unroll
        for (int hh = 0; hh < 2; ++hh) {
            const int c = (w * 2 + hh) * 16 + m;
            #pragma unroll
            for (int kb = 0; kb < 4; ++kb) {
                float wf[8];
                #pragma unroll
                for (int j = 0; j < 8; ++j) wf[j] = W2[(size_t)(kb * 32 + q * 8 + j) * 128 + c];
                wp[hh * 4 + kb] = pack_rne8(wf);
            }
        }
        #pragma unroll
        for (int hh = 0; hh < 2; ++hh) {
            const int c = (w * 2 + hh) * 16 + m;
            float bb = b2[c];
            f32x4 acc = {bb, bb, bb, bb};
            #pragma unroll
            for (int kb = 0; kb < 4; ++kb)
                acc = __builtin_amdgcn_mfma_f32_16x16x32_bf16(ax[kb], wp[hh * 4 + kb], acc, 0, 0, 0);
            uint2 pk;
            pk.x = (unsigned)f2bf(acc[0]) | ((unsigned)f2bf(acc[1]) << 16);
            pk.y = (unsigned)f2bf(acc[2]) | ((unsigned)f2bf(acc[3]) << 16);
            *(uint2*)(&xlT_bf[(size_t)c * 2048 + i0 + q * 4]) = pk;
        }
    }
}

// ---------------- Kernel 2: fused adjacency + A@x_last, half-j per block ----------------
// grid (128 i-tiles, 2 halves) x 512 thr (8 waves). Block = 16 rows x 1024
// cols, 8 strips of 128, double-buffered P, ONE barrier per strip (R12's
// proven pattern). Wave w owns col-group w*16..w*16+15 within a strip (S)
// and output-col group w*16..w*16+15 (AX). Partials: 2 per row.
__global__ __launch_bounds__(512, 4) void k2h(
    const unsigned short* __restrict__ emb_bf,
    const unsigned short* __restrict__ xlT_bf,
    const float* __restrict__ sq,
    const float* __restrict__ tempp, const float* __restrict__ thetap,
    float* __restrict__ adjw,      // [2048][2048] f32
    float* __restrict__ outPart,   // [2][2048][128] f32
    float* __restrict__ degPart)   // [2][2048]
{
    constexpr int LDP = 132;
    __shared__ float Pt[2][16 * LDP];
    __shared__ float degS[8][16];

    const int t = threadIdx.x;
    const int lane = t & 63;
    const int w = t >> 6;          // wave 0..7
    const int m = lane & 15;
    const int q = lane >> 4;
    const int i0 = blockIdx.x * 16;
    const int half = blockIdx.y;   // 0/1
    const int jbase = half * 1024;
    const float scale = 1.0f + tempp[0];
    const float bias = 5.0f + thetap[0];

    // A-fragments of emb rows i0..i0+15 (K=64)
    bf16x8 a0 = *(const bf16x8*)(emb_bf + (size_t)(i0 + m) * 64 + q * 8);
    bf16x8 a1 = *(const bf16x8*)(emb_bf + (size_t)(i0 + m) * 64 + 32 + q * 8);
    float sqIr[4];
    #pragma unroll
    for (int r = 0; r < 4; ++r) sqIr[r] = sq[i0 + q * 4 + r];

    f32x4 accO = {0.f, 0.f, 0.f, 0.f};       // out rows q*4+r, col w*16+m
    float dega[4] = {0.f, 0.f, 0.f, 0.f};
    const int cg = w * 16;                    // output col-group (AX)

    for (int jt = 0; jt < 8; ++jt) {
        const int j0 = jbase + jt * 128;
        float* P = &Pt[jt & 1][0];

        // prefetch AX B-fragments (xlT rows cg..cg+15, k = strip cols)
        bf16x8 xb[4];
        #pragma unroll
        for (int s = 0; s < 4; ++s)
            xb[s] = *(const bf16x8*)(xlT_bf + (size_t)(cg + m) * 2048 + j0 + s * 32 + q * 8);

        // S phase: wave w computes strip cols w*16..w*16+15
        {
            const int col = w * 16 + m;
            const int gcol = j0 + col;
            const unsigned short* ebj = emb_bf + (size_t)gcol * 64;
            bf16x8 b0 = *(const bf16x8*)(ebj + q * 8);
            bf16x8 b1 = *(const bf16x8*)(ebj + 32 + q * 8);
            f32x4 S = {0.f, 0.f, 0.f, 0.f};
            S = __builtin_amdgcn_mfma_f32_16x16x32_bf16(a0, b0, S, 0, 0, 0);
            S = __builtin_amdgcn_mfma_f32_16x16x32_bf16(a1, b1, S, 0, 0, 0);

            const float csqJ = sq[gcol];
            #pragma unroll
            for (int r = 0; r < 4; ++r) {
                int grow = i0 + q * 4 + r;
                float dist = 2.0f * S[r] - sqIr[r] - csqJ;
                float z = scale * dist + bias;
                float p = __builtin_amdgcn_rcpf(1.0f + __expf(-z));
                if (grow == gcol) p += 1.0f;
                dega[r] += p;
                P[(q * 4 + r) * LDP + col] = p;
            }
        }
        __syncthreads();

        // adjw store: 512 thr x one f32x4 = 32 lanes x 16B per row-pair ->
        // full 128B lines, 8KB per strip.
        {
            int row = t >> 5;            // 0..15
            int c0 = (t & 31) * 4;       // f32 col 0..124
            f32x4 v = *(const f32x4*)(&P[row * LDP + c0]);
            *(f32x4*)(adjw + (size_t)(i0 + row) * 2048 + j0 + c0) = v;
        }

        // AX: accO += P(16x128) @ xlT(128 x 16-col-group), K=128
        #pragma unroll
        for (int s = 0; s < 4; ++s) {
            float af[8];
            *(f32x4*)(&af[0]) = *(const f32x4*)(&P[m * LDP + s * 32 + q * 8]);
            *(f32x4*)(&af[4]) = *(const f32x4*)(&P[m * LDP + s * 32 + q * 8 + 4]);
            bf16x8 aa = pack_bf8(af);
            accO = __builtin_amdgcn_mfma_f32_16x16x32_bf16(aa, xb[s], accO, 0, 0, 0);
        }
        // next strip's S writes the other P buffer; the barrier at the top of
        // the next iteration orders AX(jt) before S(jt+2) buffer reuse.
    }

    // deg half-partial: reduce over m-lanes, combine 8 waves via LDS
    #pragma unroll
    for (int r = 0; r < 4; ++r) {
        float v = dega[r];
        v += __shfl_xor(v, 1);
        v += __shfl_xor(v, 2);
        v += __shfl_xor(v, 4);
        v += __shfl_xor(v, 8);
        if (m == 0) degS[w][q * 4 + r] = v;
    }
    __syncthreads();
    if (t < 16) {
        float d = 0.f;
        #pragma unroll
        for (int ww = 0; ww < 8; ++ww) d += degS[ww][t];
        degPart[half * 2048 + i0 + t] = d;
    }

    // out half-partial: rows q*4+r, col cg+m (scatter; only 2MB scratch)
    float* op = outPart + (size_t)half * 262144 + (size_t)i0 * 128 + cg + m;
    #pragma unroll
    for (int r = 0; r < 4; ++r)
        op[(size_t)(q * 4 + r) * 128] = accO[r];
}

// ---------------- Kernel 3: out = relu((o0+o1)/(d0+d1)), f32x4 ----------------
__global__ __launch_bounds__(256) void k3_fin(
    const float* __restrict__ outPart, const float* __restrict__ degPart,
    float* __restrict__ out)
{
    int gid = blockIdx.x * 256 + threadIdx.x;   // 65536 = 2048 x 32
    int i = gid >> 5;
    int c0 = (gid & 31) * 4;
    f32x4 v0 = *(const f32x4*)(outPart + (size_t)i * 128 + c0);
    f32x4 v1 = *(const f32x4*)(outPart + 262144 + (size_t)i * 128 + c0);
    float dinv = 1.0f / (degPart[i] + degPart[2048 + i]);
    f32x4 o;
    #pragma unroll
    for (int r = 0; r < 4; ++r) o[r] = fmaxf((v0[r] + v1[r]) * dinv, 0.f);
    *(f32x4*)(out + (size_t)i * 128 + c0) = o;
}

extern "C" void kernel_launch(void* const* d_in, const int* in_sizes, int n_in,
                              void* d_out, int out_size, void* d_ws, size_t ws_size,
                              hipStream_t stream) {
    (void)in_sizes; (void)n_in; (void)out_size; (void)ws_size;
    const float* x     = (const float*)d_in[0];
    const float* W0    = (const float*)d_in[2];
    const float* b0    = (const float*)d_in[3];
    const float* W1    = (const float*)d_in[4];
    const float* b1    = (const float*)d_in[5];
    const float* W2    = (const float*)d_in[6];
    const float* b2    = (const float*)d_in[7];
    const float* temp  = (const float*)d_in[8];
    const float* theta = (const float*)d_in[9];

    char* ws = (char*)d_ws;
    unsigned short* emb_bf = (unsigned short*)(ws);            // ->262144
    unsigned short* xlT_bf = (unsigned short*)(ws + 262144);   // ->786432
    float* sq      = (float*)(ws + 786432);                    // ->794624
    float* degPart = (float*)(ws + 794624);                    // 2x2048x4 ->811008
    float* outPart = (float*)(ws + 811008);                    // 2x2048x128x4 ->2908160

    float* out  = (float*)d_out;              // [2048*128]
    float* adjw = (float*)d_out + 262144;     // [2048*2048]

    k1_mfma<<<256, 256, 0, stream>>>(x, W0, b0, W1, b1, W2, b2,
                                     emb_bf, xlT_bf, sq);
    k2h<<<dim3(128, 2), 512, 0, stream>>>(emb_bf, xlT_bf, sq, temp, theta,
                                          adjw, outPart, degPart);
    k3_fin<<<256, 256, 0, stream>>>(outPart, degPart, out);
}